// Round 8
// baseline (213.170 us; speedup 1.0000x reference)
//
#include <hip/hip_runtime.h>

// CLM_26594437496868: co-attention (dual-softmax) + conv3x3 + BN + LeakyReLU
// b=4, c=64, h=w=64, hw=4096.
//
// R7: attn was VALU-bound (R6: VALUBusy 55%, MfmaUtil 25%).
//  - Q prescaled by log2e in prep (separate _s copies; each buffer is Q in
//    one pass and K in the other) -> kills 16 v_mul/iter.
//  - P f32->bf16 packing via v_cvt_pk_bf16_f32 (1 op per pair vs ~7).
//  - l row-sums via ones-MFMA on the idle matrix pipe (kills 16 adds/iter
//    and the final shuffles).
//  - merge kernel deleted: Opart stored bf16 (half traffic), tiny lred
//    kernel builds linv = 1/sum_s l, conv merges Opart*linv inline.
//  - bf16 Opart halves split-buffer size -> same ws affords S=4 (grid 2048).

typedef short bf16x8 __attribute__((ext_vector_type(8)));
typedef float f32x4 __attribute__((ext_vector_type(4)));
typedef unsigned int u32x4 __attribute__((ext_vector_type(4)));
typedef unsigned short ushort_t;
typedef ushort_t ushort8 __attribute__((ext_vector_type(8)));

#define HW 4096
#define NC 64
#define NB 4
#define L2E 1.44269504f

#define GLB(p) ((const __attribute__((address_space(1))) unsigned int*)(p))
#define LDSP(p) ((__attribute__((address_space(3))) unsigned int*)(p))

__device__ __forceinline__ ushort_t f2bf(float f) {
  unsigned u = __builtin_bit_cast(unsigned, f);
  unsigned r = u + 0x7FFFu + ((u >> 16) & 1u);
  return (ushort_t)(r >> 16);
}

__device__ __forceinline__ float bf2f(ushort_t u) {
  unsigned v = ((unsigned)u) << 16;
  return __builtin_bit_cast(float, v);
}

__device__ __forceinline__ float fast_exp2(float x) {
#if __has_builtin(__builtin_amdgcn_exp2f)
  return __builtin_amdgcn_exp2f(x);
#else
  return exp2f(x);
#endif
}

__device__ __forceinline__ unsigned cvt_pk_bf16(float lo, float hi) {
  unsigned r;
  asm("v_cvt_pk_bf16_f32 %0, %1, %2" : "=v"(r) : "v"(lo), "v"(hi));
  return r;
}

// ---------------------------------------------------------------- prep ----
// grid 512 = 4 b x 128 chunks of 32 pos. t: g = t>>5 (8 ch / 8 outs), p = t&31.
// Emits: exlT/qT (K use) and exlT_s/qT_s (Q use, prescaled by log2e),
//        bf16 [b][pos][64ch]; q_tl/ex_tl tiled [b][kvblk][64ch][64 perm kv].
__global__ __launch_bounds__(256) void prep_kernel(
    const float* __restrict__ ex, const float* __restrict__ q,
    const float* __restrict__ Wl,
    ushort_t* __restrict__ exlT, ushort_t* __restrict__ qT,
    ushort_t* __restrict__ exlT_s, ushort_t* __restrict__ qT_s,
    ushort_t* __restrict__ q_tl, ushort_t* __restrict__ ex_tl)
{
  __shared__ float exs[64][33];
  __shared__ float wls[64][64];

  const int t = threadIdx.x;
  const int b = blockIdx.x >> 7;
  const int chunk = blockIdx.x & 127;
  const int g = t >> 5;          // 0..7
  const int p = t & 31;
  const int pos = chunk * 32 + p;
  const int tile = pos >> 6;
  const int kv = pos & 63;
  // sigma^-1: kv -> stored column, so MFMA k-position p reads V[sigma(p)].
  const int vcol = ((kv >> 5) << 5) + (((kv >> 2) & 3) << 3)
                 + (((kv >> 4) & 1) << 2) + (kv & 3);

  const float* exb = ex + (size_t)b * NC * HW;
  const float* qb  = q  + (size_t)b * NC * HW;
  ushort_t* exlTb  = exlT  + (size_t)b * HW * NC;
  ushort_t* exlTsb = exlT_s+ (size_t)b * HW * NC;
  ushort_t* qTb    = qT    + (size_t)b * HW * NC;
  ushort_t* qTsb   = qT_s  + (size_t)b * HW * NC;
  ushort_t* qtlb   = q_tl  + (size_t)b * HW * NC + (size_t)tile * 4096 + vcol;
  ushort_t* etlb   = ex_tl + (size_t)b * HW * NC + (size_t)tile * 4096 + vcol;

#pragma unroll
  for (int it = 0; it < 16; ++it) {
    int idx = it * 256 + t;
    wls[idx >> 6][idx & 63] = Wl[idx];
  }

  ushort8 qh, qhs;
#pragma unroll
  for (int j = 0; j < 8; ++j) {
    int c = g * 8 + j;
    float ev = exb[c * HW + pos];
    exs[c][p] = ev;
    etlb[c * 64] = f2bf(ev);
    float qv = qb[c * HW + pos];
    qtlb[c * 64] = f2bf(qv);
    qh[j]  = f2bf(qv);
    qhs[j] = f2bf(qv * L2E);
  }
  *(ushort8*)(qTb  + (size_t)pos * NC + g * 8) = qh;
  *(ushort8*)(qTsb + (size_t)pos * NC + g * 8) = qhs;
  __syncthreads();

  // exl: out-channels g*8..g*8+8 for pos
  float acc[8];
#pragma unroll
  for (int oo = 0; oo < 8; ++oo) acc[oo] = 0.f;
  for (int c = 0; c < 64; ++c) {
    float xv = exs[c][p];
#pragma unroll
    for (int oo = 0; oo < 8; ++oo)
      acc[oo] += wls[g * 8 + oo][c] * xv;
  }
  {
    ushort8 h, hs;
#pragma unroll
    for (int oo = 0; oo < 8; ++oo) { h[oo] = f2bf(acc[oo]); hs[oo] = f2bf(acc[oo] * L2E); }
    *(ushort8*)(exlTb  + (size_t)pos * NC + g * 8) = h;
    *(ushort8*)(exlTsb + (size_t)pos * NC + g * 8) = hs;
  }
}

// ---------------------------------------------------------------- attn ----
// grid: 512*S. 4 waves/block, 16 q-rows per wave, 64/S kv-blocks of 64 each.
// LDS: double-buffered K(8KB)+V(8KB) tiles, XOR-swizzled. P in registers
// (swapped QK^T + sigma-permuted V); l row-sums via ones-MFMA.
__global__ __launch_bounds__(256, 4) void attn_kernel(
    const ushort_t* __restrict__ exlT, const ushort_t* __restrict__ qT,
    const ushort_t* __restrict__ exlT_s, const ushort_t* __restrict__ qT_s,
    const ushort_t* __restrict__ q_tl, const ushort_t* __restrict__ ex_tl,
    ushort_t* __restrict__ Opart, float* __restrict__ lpart, int ss)
{
  __shared__ char smem[32768];  // [2][K 8KB | V 8KB]

  const int gid  = blockIdx.x;
  const int S    = 1 << ss;
  const int kvs  = gid & (S - 1);
  const int qb   = (gid >> ss) & 63;
  const int b    = (gid >> (ss + 6)) & 3;
  const int pass = gid >> (ss + 8);
  const int w    = threadIdx.x >> 6;
  const int lane = threadIdx.x & 63;
  const int lr = lane & 15, lg = lane >> 4;
  const int qrow0 = qb * 64 + w * 16;

  const ushort_t* QT = (pass ? qT_s : exlT_s) + (size_t)b * HW * NC;
  const ushort_t* KT = (pass ? exlT : qT) + (size_t)b * HW * NC;
  const ushort_t* VT = (pass ? ex_tl : q_tl) + (size_t)b * HW * NC;

  bf16x8 aq[2];
  {
    const ushort_t* qp = QT + (size_t)(qrow0 + lr) * NC + lg * 8;
    aq[0] = *(const bf16x8*)(qp);
    aq[1] = *(const bf16x8*)(qp + 32);
  }

  const u32x4 onesu = {0x3F803F80u, 0x3F803F80u, 0x3F803F80u, 0x3F803F80u};
  const bf16x8 vones = __builtin_bit_cast(bf16x8, onesu);

  f32x4 O[4];
  f32x4 lacc = (f32x4){0.f, 0.f, 0.f, 0.f};
#pragma unroll
  for (int t = 0; t < 4; ++t) O[t] = (f32x4){0.f, 0.f, 0.f, 0.f};

  const int niter = 64 >> ss;
  const int kv0 = kvs * niter;

  const int db0 = w * 2048 + (lane << 4);     // lane's dest byte, call 0
#define STAGE(phase, kvb)                                                      \
  {                                                                            \
    char* Kl = smem + (phase) * 16384;                                         \
    char* Vl = Kl + 8192;                                                      \
    const char* kg = (const char*)(KT + (size_t)(kvb) * 64 * NC);              \
    const char* vg = (const char*)(VT + (size_t)(kvb) * 4096);                 \
    _Pragma("unroll")                                                          \
    for (int c2 = 0; c2 < 2; ++c2) {                                           \
      int d = db0 + c2 * 1024;                                                 \
      int swz = d ^ (((d >> 7) & 7) << 4);                                     \
      __builtin_amdgcn_global_load_lds(GLB(kg + swz),                          \
                                       LDSP(Kl + w * 2048 + c2 * 1024), 16, 0, 0); \
      __builtin_amdgcn_global_load_lds(GLB(vg + swz),                          \
                                       LDSP(Vl + w * 2048 + c2 * 1024), 16, 0, 0); \
    }                                                                          \
  }

  STAGE(0, kv0);
  __syncthreads();

  int cur = 0;
  for (int i = 0; i < niter; ++i) {
    if (i + 1 < niter) STAGE(cur ^ 1, kv0 + i + 1);

    const char* Kl = smem + cur * 16384;
    const char* Vl = Kl + 8192;
    const int cswz = (lr & 7) << 4;   // (row&7)<<4 with row = t*16+lr

    // ---- S^T = K Q^T: s[t][r] = S[kv=16t+4lg+r][q-row=lr] (log2 domain) ----
    f32x4 s[4];
#pragma unroll
    for (int t = 0; t < 4; ++t) s[t] = (f32x4){0.f, 0.f, 0.f, 0.f};
#pragma unroll
    for (int ks = 0; ks < 2; ++ks)
#pragma unroll
      for (int t = 0; t < 4; ++t) {
        bf16x8 kf = *(const bf16x8*)(Kl + (t * 16 + lr) * 128
                                     + ((ks * 64 + lg * 16) ^ cswz));
        s[t] = __builtin_amdgcn_mfma_f32_16x16x32_bf16(kf, aq[ks], s[t], 0, 0, 0);
      }

    // ---- p = exp2(s); cvt_pk packs into the two PV A-fragments ----
    unsigned int pa[2][4];
#pragma unroll
    for (int ks = 0; ks < 2; ++ks)
#pragma unroll
      for (int hf = 0; hf < 2; ++hf) {
        const int t = ks * 2 + hf;
        float p0 = fast_exp2(s[t][0]);
        float p1 = fast_exp2(s[t][1]);
        float p2 = fast_exp2(s[t][2]);
        float p3 = fast_exp2(s[t][3]);
        pa[ks][hf * 2]     = cvt_pk_bf16(p0, p1);
        pa[ks][hf * 2 + 1] = cvt_pk_bf16(p2, p3);
      }

    // ---- O += P V; l += P * ones (on the MFMA pipe) ----
#pragma unroll
    for (int ks = 0; ks < 2; ++ks) {
      u32x4 pv = {pa[ks][0], pa[ks][1], pa[ks][2], pa[ks][3]};
      bf16x8 paf = __builtin_bit_cast(bf16x8, pv);
      lacc = __builtin_amdgcn_mfma_f32_16x16x32_bf16(paf, vones, lacc, 0, 0, 0);
#pragma unroll
      for (int t = 0; t < 4; ++t) {
        bf16x8 vf = *(const bf16x8*)(Vl + (t * 16 + lr) * 128
                                     + ((ks * 64 + lg * 16) ^ cswz));
        O[t] = __builtin_amdgcn_mfma_f32_16x16x32_bf16(paf, vf, O[t], 0, 0, 0);
      }
    }

    __syncthreads();   // drains staging of next tile; releases cur
    cur ^= 1;
  }

  ushort_t* Ob = Opart + ((size_t)((pass * 4 + b) * S + kvs)) * (HW * NC);
  float* lp = lpart + ((size_t)((pass * 4 + b) * S + kvs)) * HW;
#pragma unroll
  for (int t = 0; t < 4; ++t)
#pragma unroll
    for (int r = 0; r < 4; ++r)
      Ob[(size_t)(qrow0 + lg * 4 + r) * NC + t * 16 + lr] = f2bf(O[t][r]);
  if (lr == 0) {
#pragma unroll
    for (int r = 0; r < 4; ++r) lp[qrow0 + lg * 4 + r] = lacc[r];
  }
#undef STAGE
}

// ---------------------------------------------------------------- lred ----
// linv[pp][pos] = 1 / sum_s lpart[pp*S+s][pos], pp = pass*4+b in [0,8).
__global__ __launch_bounds__(256) void lred_kernel(
    const float* __restrict__ lpart, float* __restrict__ linv, int S)
{
  const int idx = blockIdx.x * 256 + threadIdx.x;   // 32768
  const int pp  = idx >> 12;
  const int pos = idx & 4095;
  float ls = 0.f;
  for (int s = 0; s < S; ++s) ls += lpart[(size_t)(pp * S + s) * HW + pos];
  linv[idx] = 1.0f / ls;
}

// ---------------------------------------------------------------- conv ----
// grid 512 = 4 b x 64 h x 2 w-halves. Stages ex+q, merges Opart*linv inline.
__global__ __launch_bounds__(256) void conv_kernel(
    const float* __restrict__ exF, const float* __restrict__ qF,
    const ushort_t* __restrict__ Opart, const float* __restrict__ linv,
    const float* __restrict__ Wc,
    float* __restrict__ y, float* __restrict__ stats, int S)
{
  __shared__ float xls[64][3][67];
  const int t = threadIdx.x;
  const int wh = blockIdx.x & 1;
  const int h = (blockIdx.x >> 1) & 63;
  const int b = blockIdx.x >> 7;

  const float* exb = exF + (size_t)b * NC * HW;
  const float* qb  = qF  + (size_t)b * NC * HW;

#pragma unroll
  for (int ky = 0; ky < 3; ++ky) {
    int hs = h + ky - 1;
    bool valid = (hs >= 0) && (hs < 64);
    for (int it = 0; it < 16; ++it) {
      int c  = it * 4 + (t >> 6);
      int wx = t & 63;
      float v = 0.f;
      if (valid) v = exb[c * HW + hs * 64 + wx] + qb[c * HW + hs * 64 + wx];
      xls[c][ky][wx + 1] = v;
    }
  }
  if (t < 192) { int c = t & 63; int ky = t >> 6; xls[c][ky][0] = 0.f; xls[c][ky][65] = 0.f; }
  __syncthreads();

  // merge attention outputs: sum_s Opart * linv, both passes
#pragma unroll
  for (int ky = 0; ky < 3; ++ky) {
    int hs = h + ky - 1;
    if (hs >= 0 && hs < 64) {
      for (int it = 0; it < 16; ++it) {
        int wx = it * 4 + (t >> 6);
        int c  = t & 63;
        int pos = hs * 64 + wx;
        float add = 0.f;
#pragma unroll
        for (int pass = 0; pass < 2; ++pass) {
          const int pp = pass * 4 + b;
          const ushort_t* opb = Opart + (size_t)pp * S * (HW * NC)
                              + (size_t)pos * NC + c;
          float os = 0.f;
          for (int s = 0; s < S; ++s) os += bf2f(opb[(size_t)s * (HW * NC)]);
          add += os * linv[pp * HW + pos];
        }
        xls[c][ky][wx + 1] += add;
      }
    }
  }
  __syncthreads();

  const int o   = t >> 2;
  const int ws0 = wh * 32 + (t & 3) * 8;
  float acc[8];
#pragma unroll
  for (int i = 0; i < 8; ++i) acc[i] = 0.f;

  for (int c = 0; c < 64; ++c) {
#pragma unroll
    for (int ky = 0; ky < 3; ++ky) {
      const float* wp = Wc + ((o * 64 + c) * 3 + ky) * 3;
      float w0 = wp[0], w1 = wp[1], w2 = wp[2];
      const float* xr = &xls[c][ky][ws0];
      float r[10];
#pragma unroll
      for (int i = 0; i < 10; ++i) r[i] = xr[i];
#pragma unroll
      for (int i = 0; i < 8; ++i)
        acc[i] += r[i] * w0 + r[i + 1] * w1 + r[i + 2] * w2;
    }
  }

  float s1 = 0.f, s2 = 0.f;
#pragma unroll
  for (int i = 0; i < 8; ++i) { s1 += acc[i]; s2 += acc[i] * acc[i]; }
  float* yb = y + (size_t)(b * 64 + o) * HW + h * 64 + ws0;
#pragma unroll
  for (int i = 0; i < 8; ++i) yb[i] = acc[i];

  s1 += __shfl_xor(s1, 1); s1 += __shfl_xor(s1, 2);
  s2 += __shfl_xor(s2, 1); s2 += __shfl_xor(s2, 2);
  if ((t & 3) == 0) { atomicAdd(&stats[o], s1); atomicAdd(&stats[64 + o], s2); }
}

// ------------------------------------------------------------------ bn ----
__global__ __launch_bounds__(256) void bn_kernel(
    const float* __restrict__ y, const float* __restrict__ stats,
    const float* __restrict__ gamma, const float* __restrict__ beta,
    float* __restrict__ out)
{
  const int e = (blockIdx.x * 256 + threadIdx.x) * 4;
  const int o = (e >> 12) & 63;
  float mean = stats[o] * (1.f / 16384.f);
  float var  = stats[64 + o] * (1.f / 16384.f) - mean * mean;
  float g  = gamma[o] * rsqrtf(var + 1e-5f);
  float bt = beta[o] - mean * g;
  float4 v = *(const float4*)(y + e);
  float4 r;
  r.x = v.x * g + bt; r.x = r.x > 0.f ? r.x : 0.1f * r.x;
  r.y = v.y * g + bt; r.y = r.y > 0.f ? r.y : 0.1f * r.y;
  r.z = v.z * g + bt; r.z = r.z > 0.f ? r.z : 0.1f * r.z;
  r.w = v.w * g + bt; r.w = r.w > 0.f ? r.w : 0.1f * r.w;
  *(float4*)(out + e) = r;
}

// -------------------------------------------------------------- launch ----
extern "C" void kernel_launch(void* const* d_in, const int* in_sizes, int n_in,
                              void* d_out, int out_size, void* d_ws, size_t ws_size,
                              hipStream_t stream)
{
  const float* ex    = (const float*)d_in[0];
  const float* q     = (const float*)d_in[1];
  const float* Wl    = (const float*)d_in[2];
  const float* Wc    = (const float*)d_in[3];
  const float* gamma = (const float*)d_in[4];
  const float* beta  = (const float*)d_in[5];
  float* out = (float*)d_out;

  char* ws = (char*)d_ws;
  ushort_t* exlT   = (ushort_t*)(ws);                   // 2 MB bf16 [b][pos][ch] (K p1)
  ushort_t* qT     = (ushort_t*)(ws + (2u << 20));      // 2 MB bf16 [b][pos][ch] (K p0)
  ushort_t* q_tl   = (ushort_t*)(ws + (4u << 20));      // 2 MB bf16 V tiles (perm)
  ushort_t* ex_tl  = (ushort_t*)(ws + (6u << 20));      // 2 MB bf16 V tiles (perm)
  ushort_t* exlT_s = (ushort_t*)(ws + (8u << 20));      // 2 MB bf16 scaled (Q p0)
  ushort_t* qT_s   = (ushort_t*)(ws + (10u << 20));     // 2 MB bf16 scaled (Q p1)
  float* yBuf  = (float*)(ws + (12u << 20));            // 4 MB f32 [b][o][pos]
  float* stats = (float*)(ws + (16u << 20));            // 512 B
  float* lpart = (float*)(ws + (16u << 20) + 65536);    // <=512 KB
  float* linv  = (float*)(ws + (16u << 20) + 655360);   // 128 KB
  ushort_t* Opart = (ushort_t*)(ws + (17u << 20));      // S*4 MB bf16

  // kv-split factor from scratch budget: need 17MB + S*4MB
  int ss;
  if (ws_size >= (34u << 20)) ss = 2;
  else if (ws_size >= (26u << 20)) ss = 1;
  else ss = 0;
  const int S = 1 << ss;

  hipMemsetAsync(stats, 0, 128 * sizeof(float), stream);
  prep_kernel<<<512, 256, 0, stream>>>(ex, q, Wl, exlT, qT, exlT_s, qT_s, q_tl, ex_tl);
  attn_kernel<<<512 * S, 256, 0, stream>>>(exlT, qT, exlT_s, qT_s, q_tl, ex_tl,
                                           Opart, lpart, ss);
  lred_kernel<<<128, 256, 0, stream>>>(lpart, linv, S);
  conv_kernel<<<512, 256, 0, stream>>>(ex, q, Opart, linv, Wc, yBuf, stats, S);
  bn_kernel<<<1024, 256, 0, stream>>>(yBuf, stats, gamma, beta, out);
}

// Round 9
// 112.382 us; speedup vs baseline: 1.8968x; 1.8968x over previous
//
#include <hip/hip_runtime.h>

// CLM_26594437496868: co-attention (dual-softmax) + conv3x3 + BN + LeakyReLU
// b=4, c=64, h=w=64, hw=4096.
//
// R9: R8's inline merge destroyed conv (153us, FETCH 74MB: 8 strided scalar
// bf16 loads/elem). Revert to a standalone streaming merge kernel; conv back
// to R6 form. Keep R7 attn (sqrt-log2e prescale now on BOTH operands so the
// same bf16 buffers serve Q and K roles: 4 staging buffers, S=4 fits 33MB).

typedef short bf16x8 __attribute__((ext_vector_type(8)));
typedef float f32x4 __attribute__((ext_vector_type(4)));
typedef unsigned int u32x4 __attribute__((ext_vector_type(4)));
typedef unsigned short ushort_t;
typedef ushort_t ushort8 __attribute__((ext_vector_type(8)));

#define HW 4096
#define NC 64
#define NB 4
#define RT_L2E 1.2011224087864498f   // sqrt(log2 e); (a*RT)*(b*RT) = a*b*log2e

#define GLB(p) ((const __attribute__((address_space(1))) unsigned int*)(p))
#define LDSP(p) ((__attribute__((address_space(3))) unsigned int*)(p))

__device__ __forceinline__ ushort_t f2bf(float f) {
  unsigned u = __builtin_bit_cast(unsigned, f);
  unsigned r = u + 0x7FFFu + ((u >> 16) & 1u);
  return (ushort_t)(r >> 16);
}

__device__ __forceinline__ float bf2f(ushort_t u) {
  unsigned v = ((unsigned)u) << 16;
  return __builtin_bit_cast(float, v);
}

__device__ __forceinline__ float fast_exp2(float x) {
#if __has_builtin(__builtin_amdgcn_exp2f)
  return __builtin_amdgcn_exp2f(x);
#else
  return exp2f(x);
#endif
}

__device__ __forceinline__ unsigned cvt_pk_bf16(float lo, float hi) {
  unsigned r;
  asm("v_cvt_pk_bf16_f32 %0, %1, %2" : "=v"(r) : "v"(lo), "v"(hi));
  return r;
}

// ---------------------------------------------------------------- prep ----
// grid 512 = 4 b x 128 chunks of 32 pos. t: g = t>>5 (8 ch / 8 outs), p = t&31.
// Emits: exlT_s/qT_s bf16 [b][pos][64ch] scaled by sqrt(log2e) (Q AND K roles);
//        q_tl/ex_tl bf16 tiled [b][kvblk][64ch][64 sigma-permuted kv] (V).
__global__ __launch_bounds__(256) void prep_kernel(
    const float* __restrict__ ex, const float* __restrict__ q,
    const float* __restrict__ Wl,
    ushort_t* __restrict__ exlT_s, ushort_t* __restrict__ qT_s,
    ushort_t* __restrict__ q_tl, ushort_t* __restrict__ ex_tl)
{
  __shared__ float exs[64][33];
  __shared__ float wls[64][64];

  const int t = threadIdx.x;
  const int b = blockIdx.x >> 7;
  const int chunk = blockIdx.x & 127;
  const int g = t >> 5;          // 0..7
  const int p = t & 31;
  const int pos = chunk * 32 + p;
  const int tile = pos >> 6;
  const int kv = pos & 63;
  // sigma^-1: kv -> stored column, so MFMA k-position p reads V[sigma(p)].
  const int vcol = ((kv >> 5) << 5) + (((kv >> 2) & 3) << 3)
                 + (((kv >> 4) & 1) << 2) + (kv & 3);

  const float* exb = ex + (size_t)b * NC * HW;
  const float* qb  = q  + (size_t)b * NC * HW;
  ushort_t* exlTsb = exlT_s+ (size_t)b * HW * NC;
  ushort_t* qTsb   = qT_s  + (size_t)b * HW * NC;
  ushort_t* qtlb   = q_tl  + (size_t)b * HW * NC + (size_t)tile * 4096 + vcol;
  ushort_t* etlb   = ex_tl + (size_t)b * HW * NC + (size_t)tile * 4096 + vcol;

#pragma unroll
  for (int it = 0; it < 16; ++it) {
    int idx = it * 256 + t;
    wls[idx >> 6][idx & 63] = Wl[idx];
  }

  ushort8 qhs;
#pragma unroll
  for (int j = 0; j < 8; ++j) {
    int c = g * 8 + j;
    float ev = exb[c * HW + pos];
    exs[c][p] = ev;
    etlb[c * 64] = f2bf(ev);
    float qv = qb[c * HW + pos];
    qtlb[c * 64] = f2bf(qv);
    qhs[j] = f2bf(qv * RT_L2E);
  }
  *(ushort8*)(qTsb + (size_t)pos * NC + g * 8) = qhs;
  __syncthreads();

  // exl: out-channels g*8..g*8+8 for pos
  float acc[8];
#pragma unroll
  for (int oo = 0; oo < 8; ++oo) acc[oo] = 0.f;
  for (int c = 0; c < 64; ++c) {
    float xv = exs[c][p];
#pragma unroll
    for (int oo = 0; oo < 8; ++oo)
      acc[oo] += wls[g * 8 + oo][c] * xv;
  }
  {
    ushort8 hs;
#pragma unroll
    for (int oo = 0; oo < 8; ++oo) hs[oo] = f2bf(acc[oo] * RT_L2E);
    *(ushort8*)(exlTsb + (size_t)pos * NC + g * 8) = hs;
  }
}

// ---------------------------------------------------------------- attn ----
// grid: 512*S. 4 waves/block, 16 q-rows per wave, 64/S kv-blocks of 64 each.
// LDS: double-buffered K(8KB)+V(8KB) tiles, XOR-swizzled. P in registers
// (swapped QK^T + sigma-permuted V); l row-sums via ones-MFMA.
// Both operand buffers carry sqrt(log2e) -> scores land in log2 domain.
__global__ __launch_bounds__(256, 4) void attn_kernel(
    const ushort_t* __restrict__ exlT_s, const ushort_t* __restrict__ qT_s,
    const ushort_t* __restrict__ q_tl, const ushort_t* __restrict__ ex_tl,
    ushort_t* __restrict__ Opart, float* __restrict__ lpart, int ss)
{
  __shared__ char smem[32768];  // [2][K 8KB | V 8KB]

  const int gid  = blockIdx.x;
  const int S    = 1 << ss;
  const int kvs  = gid & (S - 1);
  const int qb   = (gid >> ss) & 63;
  const int b    = (gid >> (ss + 6)) & 3;
  const int pass = gid >> (ss + 8);
  const int w    = threadIdx.x >> 6;
  const int lane = threadIdx.x & 63;
  const int lr = lane & 15, lg = lane >> 4;
  const int qrow0 = qb * 64 + w * 16;

  const ushort_t* QT = (pass ? qT_s : exlT_s) + (size_t)b * HW * NC;
  const ushort_t* KT = (pass ? exlT_s : qT_s) + (size_t)b * HW * NC;
  const ushort_t* VT = (pass ? ex_tl : q_tl) + (size_t)b * HW * NC;

  bf16x8 aq[2];
  {
    const ushort_t* qp = QT + (size_t)(qrow0 + lr) * NC + lg * 8;
    aq[0] = *(const bf16x8*)(qp);
    aq[1] = *(const bf16x8*)(qp + 32);
  }

  const u32x4 onesu = {0x3F803F80u, 0x3F803F80u, 0x3F803F80u, 0x3F803F80u};
  const bf16x8 vones = __builtin_bit_cast(bf16x8, onesu);

  f32x4 O[4];
  f32x4 lacc = (f32x4){0.f, 0.f, 0.f, 0.f};
#pragma unroll
  for (int t = 0; t < 4; ++t) O[t] = (f32x4){0.f, 0.f, 0.f, 0.f};

  const int niter = 64 >> ss;
  const int kv0 = kvs * niter;

  const int db0 = w * 2048 + (lane << 4);     // lane's dest byte, call 0
#define STAGE(phase, kvb)                                                      \
  {                                                                            \
    char* Kl = smem + (phase) * 16384;                                         \
    char* Vl = Kl + 8192;                                                      \
    const char* kg = (const char*)(KT + (size_t)(kvb) * 64 * NC);              \
    const char* vg = (const char*)(VT + (size_t)(kvb) * 4096);                 \
    _Pragma("unroll")                                                          \
    for (int c2 = 0; c2 < 2; ++c2) {                                           \
      int d = db0 + c2 * 1024;                                                 \
      int swz = d ^ (((d >> 7) & 7) << 4);                                     \
      __builtin_amdgcn_global_load_lds(GLB(kg + swz),                          \
                                       LDSP(Kl + w * 2048 + c2 * 1024), 16, 0, 0); \
      __builtin_amdgcn_global_load_lds(GLB(vg + swz),                          \
                                       LDSP(Vl + w * 2048 + c2 * 1024), 16, 0, 0); \
    }                                                                          \
  }

  STAGE(0, kv0);
  __syncthreads();

  int cur = 0;
  for (int i = 0; i < niter; ++i) {
    if (i + 1 < niter) STAGE(cur ^ 1, kv0 + i + 1);

    const char* Kl = smem + cur * 16384;
    const char* Vl = Kl + 8192;
    const int cswz = (lr & 7) << 4;   // (row&7)<<4 with row = t*16+lr

    // ---- S^T = K Q^T: s[t][r] = S[kv=16t+4lg+r][q-row=lr] (log2 domain) ----
    f32x4 s[4];
#pragma unroll
    for (int t = 0; t < 4; ++t) s[t] = (f32x4){0.f, 0.f, 0.f, 0.f};
#pragma unroll
    for (int ks = 0; ks < 2; ++ks)
#pragma unroll
      for (int t = 0; t < 4; ++t) {
        bf16x8 kf = *(const bf16x8*)(Kl + (t * 16 + lr) * 128
                                     + ((ks * 64 + lg * 16) ^ cswz));
        s[t] = __builtin_amdgcn_mfma_f32_16x16x32_bf16(kf, aq[ks], s[t], 0, 0, 0);
      }

    // ---- p = exp2(s); cvt_pk packs into the two PV A-fragments ----
    unsigned int pa[2][4];
#pragma unroll
    for (int ks = 0; ks < 2; ++ks)
#pragma unroll
      for (int hf = 0; hf < 2; ++hf) {
        const int t = ks * 2 + hf;
        float p0 = fast_exp2(s[t][0]);
        float p1 = fast_exp2(s[t][1]);
        float p2 = fast_exp2(s[t][2]);
        float p3 = fast_exp2(s[t][3]);
        pa[ks][hf * 2]     = cvt_pk_bf16(p0, p1);
        pa[ks][hf * 2 + 1] = cvt_pk_bf16(p2, p3);
      }

    // ---- O += P V; l += P * ones (on the MFMA pipe) ----
#pragma unroll
    for (int ks = 0; ks < 2; ++ks) {
      u32x4 pv = {pa[ks][0], pa[ks][1], pa[ks][2], pa[ks][3]};
      bf16x8 paf = __builtin_bit_cast(bf16x8, pv);
      lacc = __builtin_amdgcn_mfma_f32_16x16x32_bf16(paf, vones, lacc, 0, 0, 0);
#pragma unroll
      for (int t = 0; t < 4; ++t) {
        bf16x8 vf = *(const bf16x8*)(Vl + (t * 16 + lr) * 128
                                     + ((ks * 64 + lg * 16) ^ cswz));
        O[t] = __builtin_amdgcn_mfma_f32_16x16x32_bf16(paf, vf, O[t], 0, 0, 0);
      }
    }

    __syncthreads();   // drains staging of next tile; releases cur
    cur ^= 1;
  }

  ushort_t* Ob = Opart + ((size_t)((pass * 4 + b) * S + kvs)) * (HW * NC);
  float* lp = lpart + ((size_t)((pass * 4 + b) * S + kvs)) * HW;
#pragma unroll
  for (int t = 0; t < 4; ++t)
#pragma unroll
    for (int r = 0; r < 4; ++r)
      Ob[(size_t)(qrow0 + lg * 4 + r) * NC + t * 16 + lr] = f2bf(O[t][r]);
  if (lr == 0) {
#pragma unroll
    for (int r = 0; r < 4; ++r) lp[qrow0 + lg * 4 + r] = lacc[r];
  }
#undef STAGE
}

// ---------------------------------------------------------------- lred ----
// linv[pp][pos] = 1 / sum_s lpart[pp*S+s][pos], pp = pass*4+b in [0,8).
__global__ __launch_bounds__(256) void lred_kernel(
    const float* __restrict__ lpart, float* __restrict__ linv, int S)
{
  const int idx = blockIdx.x * 256 + threadIdx.x;   // 32768
  const int pp  = idx >> 12;
  const int pos = idx & 4095;
  float ls = 0.f;
  for (int s = 0; s < S; ++s) ls += lpart[(size_t)(pp * S + s) * HW + pos];
  linv[idx] = 1.0f / ls;
}

// --------------------------------------------------------------- merge ----
// Osum[b][pos][ch] = sum_pass (sum_s Opart_bf16) * linv[pp][pos]. Streaming,
// fully coalesced: thread handles 8 ch (ushort8 per buffer).
__global__ __launch_bounds__(256) void merge_kernel(
    const ushort_t* __restrict__ Opart, const float* __restrict__ linv,
    float* __restrict__ Osum, int S)
{
  const int idx = blockIdx.x * 256 + threadIdx.x;   // 131072 total
  const int c8  = (idx & 7) * 8;
  const int pos = (idx >> 3) & 4095;
  const int b   = idx >> 15;

  float acc[8];
#pragma unroll
  for (int j = 0; j < 8; ++j) acc[j] = 0.f;

#pragma unroll
  for (int pass = 0; pass < 2; ++pass) {
    const int pp = pass * 4 + b;
    const ushort_t* opb = Opart + (size_t)pp * S * (HW * NC)
                        + (size_t)pos * NC + c8;
    float os[8];
#pragma unroll
    for (int j = 0; j < 8; ++j) os[j] = 0.f;
    for (int s = 0; s < S; ++s) {
      ushort8 v = *(const ushort8*)(opb + (size_t)s * (HW * NC));
#pragma unroll
      for (int j = 0; j < 8; ++j) os[j] += bf2f(v[j]);
    }
    float inv = linv[pp * HW + pos];
#pragma unroll
    for (int j = 0; j < 8; ++j) acc[j] += os[j] * inv;
  }

  float* ob = Osum + (size_t)b * (HW * NC) + (size_t)pos * NC + c8;
  *(float4*)(ob)     = (float4){acc[0], acc[1], acc[2], acc[3]};
  *(float4*)(ob + 4) = (float4){acc[4], acc[5], acc[6], acc[7]};
}

// ---------------------------------------------------------------- conv ----
// grid 512 = 4 b x 64 h x 2 w-halves. Full-width staging, half-width compute.
__global__ __launch_bounds__(256) void conv_kernel(
    const float* __restrict__ exF, const float* __restrict__ qF,
    const float* __restrict__ OS, const float* __restrict__ Wc,
    float* __restrict__ y, float* __restrict__ stats)
{
  __shared__ float xls[64][3][67];
  const int t = threadIdx.x;
  const int wh = blockIdx.x & 1;
  const int h = (blockIdx.x >> 1) & 63;
  const int b = blockIdx.x >> 7;

  const float* exb = exF + (size_t)b * NC * HW;
  const float* qb  = qF  + (size_t)b * NC * HW;
  const float* OSb = OS + (size_t)b * HW * NC;

#pragma unroll
  for (int ky = 0; ky < 3; ++ky) {
    int hs = h + ky - 1;
    bool valid = (hs >= 0) && (hs < 64);
    for (int it = 0; it < 16; ++it) {
      int c  = it * 4 + (t >> 6);
      int wx = t & 63;
      float v = 0.f;
      if (valid) v = exb[c * HW + hs * 64 + wx] + qb[c * HW + hs * 64 + wx];
      xls[c][ky][wx + 1] = v;
    }
  }
  if (t < 192) { int c = t & 63; int ky = t >> 6; xls[c][ky][0] = 0.f; xls[c][ky][65] = 0.f; }
  __syncthreads();

#pragma unroll
  for (int ky = 0; ky < 3; ++ky) {
    int hs = h + ky - 1;
    if (hs >= 0 && hs < 64) {
      for (int it = 0; it < 16; ++it) {
        int wx = it * 4 + (t >> 6);
        int c  = t & 63;
        xls[c][ky][wx + 1] += OSb[(size_t)(hs * 64 + wx) * NC + c];
      }
    }
  }
  __syncthreads();

  const int o   = t >> 2;
  const int ws0 = wh * 32 + (t & 3) * 8;
  float acc[8];
#pragma unroll
  for (int i = 0; i < 8; ++i) acc[i] = 0.f;

  for (int c = 0; c < 64; ++c) {
#pragma unroll
    for (int ky = 0; ky < 3; ++ky) {
      const float* wp = Wc + ((o * 64 + c) * 3 + ky) * 3;
      float w0 = wp[0], w1 = wp[1], w2 = wp[2];
      const float* xr = &xls[c][ky][ws0];
      float r[10];
#pragma unroll
      for (int i = 0; i < 10; ++i) r[i] = xr[i];
#pragma unroll
      for (int i = 0; i < 8; ++i)
        acc[i] += r[i] * w0 + r[i + 1] * w1 + r[i + 2] * w2;
    }
  }

  float s1 = 0.f, s2 = 0.f;
#pragma unroll
  for (int i = 0; i < 8; ++i) { s1 += acc[i]; s2 += acc[i] * acc[i]; }
  float* yb = y + (size_t)(b * 64 + o) * HW + h * 64 + ws0;
#pragma unroll
  for (int i = 0; i < 8; ++i) yb[i] = acc[i];

  s1 += __shfl_xor(s1, 1); s1 += __shfl_xor(s1, 2);
  s2 += __shfl_xor(s2, 1); s2 += __shfl_xor(s2, 2);
  if ((t & 3) == 0) { atomicAdd(&stats[o], s1); atomicAdd(&stats[64 + o], s2); }
}

// ------------------------------------------------------------------ bn ----
__global__ __launch_bounds__(256) void bn_kernel(
    const float* __restrict__ y, const float* __restrict__ stats,
    const float* __restrict__ gamma, const float* __restrict__ beta,
    float* __restrict__ out)
{
  const int e = (blockIdx.x * 256 + threadIdx.x) * 4;
  const int o = (e >> 12) & 63;
  float mean = stats[o] * (1.f / 16384.f);
  float var  = stats[64 + o] * (1.f / 16384.f) - mean * mean;
  float g  = gamma[o] * rsqrtf(var + 1e-5f);
  float bt = beta[o] - mean * g;
  float4 v = *(const float4*)(y + e);
  float4 r;
  r.x = v.x * g + bt; r.x = r.x > 0.f ? r.x : 0.1f * r.x;
  r.y = v.y * g + bt; r.y = r.y > 0.f ? r.y : 0.1f * r.y;
  r.z = v.z * g + bt; r.z = r.z > 0.f ? r.z : 0.1f * r.z;
  r.w = v.w * g + bt; r.w = r.w > 0.f ? r.w : 0.1f * r.w;
  *(float4*)(out + e) = r;
}

// -------------------------------------------------------------- launch ----
extern "C" void kernel_launch(void* const* d_in, const int* in_sizes, int n_in,
                              void* d_out, int out_size, void* d_ws, size_t ws_size,
                              hipStream_t stream)
{
  const float* ex    = (const float*)d_in[0];
  const float* q     = (const float*)d_in[1];
  const float* Wl    = (const float*)d_in[2];
  const float* Wc    = (const float*)d_in[3];
  const float* gamma = (const float*)d_in[4];
  const float* beta  = (const float*)d_in[5];
  float* out = (float*)d_out;

  char* ws = (char*)d_ws;
  ushort_t* exlT_s = (ushort_t*)(ws);                   // 2 MB bf16 [b][pos][ch] *rt
  ushort_t* qT_s   = (ushort_t*)(ws + (2u << 20));      // 2 MB bf16 [b][pos][ch] *rt
  ushort_t* q_tl   = (ushort_t*)(ws + (4u << 20));      // 2 MB bf16 V tiles (perm)
  ushort_t* ex_tl  = (ushort_t*)(ws + (6u << 20));      // 2 MB bf16 V tiles (perm)
  float* Osum  = (float*)(ws + (8u << 20));             // 4 MB f32 [b][pos][ch]
  float* yBuf  = (float*)(ws + (12u << 20));            // 4 MB f32 [b][o][pos]
  float* stats = (float*)(ws + (16u << 20));            // 512 B
  float* lpart = (float*)(ws + (16u << 20) + 65536);    // <=512 KB
  float* linv  = (float*)(ws + (16u << 20) + 655360);   // 128 KB
  ushort_t* Opart = (ushort_t*)(ws + (17u << 20));      // S*4 MB bf16

  // kv-split factor from scratch budget: need 17MB + S*4MB
  int ss;
  if (ws_size >= (33u << 20)) ss = 2;
  else if (ws_size >= (25u << 20)) ss = 1;
  else ss = 0;
  const int S = 1 << ss;

  hipMemsetAsync(stats, 0, 128 * sizeof(float), stream);
  prep_kernel<<<512, 256, 0, stream>>>(ex, q, Wl, exlT_s, qT_s, q_tl, ex_tl);
  attn_kernel<<<512 * S, 256, 0, stream>>>(exlT_s, qT_s, q_tl, ex_tl,
                                           Opart, lpart, ss);
  lred_kernel<<<128, 256, 0, stream>>>(lpart, linv, S);
  merge_kernel<<<512, 256, 0, stream>>>(Opart, linv, Osum, S);
  conv_kernel<<<512, 256, 0, stream>>>(ex, q, Osum, Wc, yBuf, stats);
  bn_kernel<<<1024, 256, 0, stream>>>(yBuf, stats, gamma, beta, out);
}